// Round 11
// baseline (23794.849 us; speedup 1.0000x reference)
//
#include <hip/hip_runtime.h>

// LSTM: B=8192, T=2048, D=1, H=256, C=10
// Persistent: 256 WGs x 512 threads (1/CU), 32 batch rows per WG.
// Per step: (32x256)@(256x1024) via v_mfma_f32_16x16x32_f16.
// R16 = R9 (best: 11.66 ms bench) + kk=2,3 held in the idle register space.
//  - Budget: waves_per_eu(2,2) -> 256 regs/wave (512/SIMD / 2 waves).
//    R9 used 128 arch + 64 AGPR acc = 192; 64 regs/wave idle. gfx950 MFMA
//    reads B operands from AGPRs directly (unified file), so 16 half8
//    B-frags (wres[2][2][4], loop-invariant, statically indexed) fit there.
//  - Stream shrinks kk=2..7 -> kk=4..7: 16 chunks/step, 256 KB/CU/step
//    from L2 (was 384). Ring sbuf[4][2] depth 4, distance 4, 16%4==0
//    keeps the mod-16 wrap across the lgkm-only step barriers static;
//    issue-slot != read-slot within an iteration (R14 lesson).
//  - kk=0,1 stay LDS-resident (128 KB, R9's plain [kk][s][t] layout).
//  - R15's one verified win kept: no hn staging (c/h update between
//    B1/B2, register-only, -8 regs). Everything else is R9 verbatim
//    (R15 lesson: micro-perturbations of R9 are noise-to-negative).
//  - Gates: t completes at streamed chunk m=12+t (kk=7) -> ACT 0/1/2
//    inline at m=12/13/14, ACT(3) + update in the tail.
//  - Spill diagnostic: FETCH in GBs => allocator sent invariants to
//    scratch (R7 mode) => revert to R9 verbatim.
// d_ws: 512 KB fp16 B-frags, byte off = kk*65536 + s*4096 + t*1024 + lane*16.

#define TT 2048
#define HH 256
#define CC 10

typedef _Float16 half8 __attribute__((ext_vector_type(8)));
typedef float float4v __attribute__((ext_vector_type(4)));

// LDS map (bytes)
#define WRES_OFF  0                      // kk=0,1 resident: 128 KB
#define HF_OFF    131072                 // h, A-frag order: 16 KB
#define BW_OFF    147456                 // bias[4][256] f32
#define WW_OFF    151552                 // w_x[4][256] f32
#define XS_OFF    155648                 // x[32 rows][32 steps] f32
#define LDS_TOTAL 159744

__device__ __forceinline__ float frcp(float v)  { return __builtin_amdgcn_rcpf(v); }
__device__ __forceinline__ float fex2(float v)  { return __builtin_amdgcn_exp2f(v); }
__device__ __forceinline__ float fsig(float v)  { return frcp(1.0f + fex2(-1.442695040888963f * v)); }
__device__ __forceinline__ float ftanh(float v) { return 2.0f * frcp(1.0f + fex2(-2.885390081777927f * v)) - 1.0f; }

#define BARRIER_LGKM() asm volatile("s_waitcnt lgkmcnt(0)\n\ts_barrier" ::: "memory")

// Pack W_{g,i,f,o}h (fp32 [256][256], row k, col j) into fp16 MFMA B-frag order.
// unit u = ((kk*16+s)*4+t)*64 + lane ; elem j: k = kk*32 + (lane>>4)*8 + j,
// gate t, hidden col j_h = s*16 + (lane&15).
__global__ void pack_weights(const float* __restrict__ Wg, const float* __restrict__ Wi,
                             const float* __restrict__ Wf, const float* __restrict__ Wo,
                             _Float16* __restrict__ wsW) {
    int u = blockIdx.x * blockDim.x + threadIdx.x;   // 32768 units
    int kk = u >> 12, rem = u & 4095;
    int s = rem >> 8, rem2 = rem & 255;
    int t = rem2 >> 6, lane = rem2 & 63;
    int q = lane >> 4, l15 = lane & 15;
    int jh = s * 16 + l15;
    const float* Wsrc = (t == 0) ? Wg : (t == 1) ? Wi : (t == 2) ? Wf : Wo;
    half8 v;
#pragma unroll
    for (int j = 0; j < 8; ++j) {
        int k = kk * 32 + q * 8 + j;
        v[j] = (_Float16)Wsrc[k * HH + jh];
    }
    ((half8*)wsW)[u] = v;
}

#define ACT_GATE(g)                                                            \
    _Pragma("unroll")                                                          \
    for (int sp_ = 0; sp_ < 2; ++sp_)                                          \
        _Pragma("unroll")                                                      \
        for (int mt_ = 0; mt_ < 2; ++mt_)                                      \
            _Pragma("unroll")                                                  \
            for (int r_ = 0; r_ < 4; ++r_)                                     \
                acc[mt_][sp_][g][r_] = ((g) == 0) ? ftanh(acc[mt_][sp_][g][r_])\
                                                  : fsig(acc[mt_][sp_][g][r_]);

__attribute__((amdgpu_waves_per_eu(2, 2)))
__global__ void __launch_bounds__(512) lstm_main(
    const float* __restrict__ x, const _Float16* __restrict__ wsW,
    const float* __restrict__ Wgx, const float* __restrict__ Wix,
    const float* __restrict__ Wfx, const float* __restrict__ Wox,
    const float* __restrict__ bg, const float* __restrict__ bi,
    const float* __restrict__ bfp, const float* __restrict__ bo,
    const float* __restrict__ Wp, const float* __restrict__ bp,
    float* __restrict__ out)
{
    extern __shared__ char smem[];
    _Float16* hf  = (_Float16*)(smem + HF_OFF);
    float*    bwL = (float*)(smem + BW_OFF);
    float*    wwL = (float*)(smem + WW_OFF);
    float*    xsL = (float*)(smem + XS_OFF);

    const int tid  = threadIdx.x;
    const int wv   = tid >> 6;          // wave 0..7
    const int lane = tid & 63;
    const int q    = lane >> 4;
    const int l15  = lane & 15;
    const int s0   = wv * 2;            // this wave's first col-slice
    const int b0   = blockIdx.x * 32;

    // ---- prologue ----
    for (int i = tid; i < 8192; i += 512) hf[i] = (_Float16)0.f;    // h0 = 0
    {   // stage kk=0,1 into LDS (frag layout preserved): 128 KB
        const uint4* src = (const uint4*)wsW;
        uint4* dst = (uint4*)(smem + WRES_OFF);
        for (int i = tid; i < 131072 / 16; i += 512) dst[i] = src[i];
    }
    {   // stage biases and x-weights
        const float* bptr[4] = { bg, bi, bfp, bo };
        const float* wptr[4] = { Wgx, Wix, Wfx, Wox };
        for (int i = tid; i < 1024; i += 512) {
            int t = i >> 8, j = i & 255;
            bwL[i] = bptr[t][j];
            wwL[i] = wptr[t][j];
        }
    }
    __syncthreads();

    // per-lane pointers
    const char* wl = (const char*)wsW + s0 * 4096 + lane * 16;      // + kk*65536 + sp*4096 + t*1024
    const char* lb = smem + WRES_OFF + s0 * 4096 + lane * 16;       // resident reads

    // kk=2,3 held in registers for the whole kernel (loop-invariant,
    // statically indexed -> register file; AGPR-eligible as MFMA B operands)
    half8 wres[2][2][4];
#pragma unroll
    for (int c = 0; c < 2; ++c)
#pragma unroll
        for (int sp = 0; sp < 2; ++sp)
#pragma unroll
            for (int t = 0; t < 4; ++t)
                wres[c][sp][t] = *(const half8*)(wl + (2 + c) * 65536 + sp * 4096 + t * 1024);

    // prime register ring: chunks 0..3 = (kk=4, t=0..3)
    half8 sbuf[4][2];
#pragma unroll
    for (int m = 0; m < 4; ++m)
#pragma unroll
        for (int sp = 0; sp < 2; ++sp)
            sbuf[m][sp] = *(const half8*)(wl + 4 * 65536 + sp * 4096 + m * 1024);

    float4v cst[2][2];
#pragma unroll
    for (int mt = 0; mt < 2; ++mt)
#pragma unroll
        for (int sp = 0; sp < 2; ++sp) cst[mt][sp] = (float4v){0.f, 0.f, 0.f, 0.f};

    // h-write scatter base (A-frag order): col j = 32wv+sp*16+l15, row mt*16+q*4+r
    const int wb = wv * 512 + ((l15 >> 3) * 16 + q * 4) * 8 + (l15 & 7);  // + mt*4096 + sp*256 + r*8

#define AREAD(kkv, mtv) (*(const half8*)(hf + (mtv) * 4096 + (kkv) * 512 + lane * 8))

    // ---- time loop ----
#pragma unroll 1
    for (int ts = 0; ts < TT; ++ts) {
        // x staging: once per 32 steps (its compiler vmcnt wait briefly drains
        // the stream queue; amortized)
        if ((ts & 31) == 0) {
            const int row = tid >> 4;            // 0..31
            const int c2  = (tid & 15) * 2;      // 0,2,..,30
            float2 xv2 = *(const float2*)&x[(b0 + row) * TT + ts + c2];
            *(float2*)&xsL[row * 32 + c2] = xv2;
            BARRIER_LGKM();
        }

        float xv[2][4];
#pragma unroll
        for (int mt = 0; mt < 2; ++mt)
#pragma unroll
            for (int r = 0; r < 4; ++r)
                xv[mt][r] = xsL[(mt * 16 + q * 4 + r) * 32 + (ts & 31)];

        // acc init = bias + x_t * W_x (fp32, exact)
        float4v acc[2][2][4];
#pragma unroll
        for (int sp = 0; sp < 2; ++sp) {
            const int jj = (s0 + sp) * 16 + l15;
#pragma unroll
            for (int t = 0; t < 4; ++t) {
                const float bb = bwL[t * 256 + jj];
                const float wx = wwL[t * 256 + jj];
#pragma unroll
                for (int mt = 0; mt < 2; ++mt)
#pragma unroll
                    for (int r = 0; r < 4; ++r)
                        acc[mt][sp][t][r] = bb + xv[mt][r] * wx;
            }
        }

        half8 a0, a1;
        // kk=0,1: resident in LDS
#pragma unroll
        for (int kk = 0; kk < 2; ++kk) {
            a0 = AREAD(kk, 0); a1 = AREAD(kk, 1);
#pragma unroll
            for (int sp = 0; sp < 2; ++sp)
#pragma unroll
                for (int t = 0; t < 4; ++t) {
                    half8 bf = *(const half8*)(lb + kk * 65536 + sp * 4096 + t * 1024);
                    acc[0][sp][t] = __builtin_amdgcn_mfma_f32_16x16x32_f16(a0, bf, acc[0][sp][t], 0, 0, 0);
                    acc[1][sp][t] = __builtin_amdgcn_mfma_f32_16x16x32_f16(a1, bf, acc[1][sp][t], 0, 0, 0);
                }
        }
        // kk=2,3: resident in registers
#pragma unroll
        for (int kk = 2; kk < 4; ++kk) {
            a0 = AREAD(kk, 0); a1 = AREAD(kk, 1);
#pragma unroll
            for (int sp = 0; sp < 2; ++sp)
#pragma unroll
                for (int t = 0; t < 4; ++t) {
                    const half8 bf = wres[kk - 2][sp][t];
                    acc[0][sp][t] = __builtin_amdgcn_mfma_f32_16x16x32_f16(a0, bf, acc[0][sp][t], 0, 0, 0);
                    acc[1][sp][t] = __builtin_amdgcn_mfma_f32_16x16x32_f16(a1, bf, acc[1][sp][t], 0, 0, 0);
                }
        }

        // kk=4..7 streamed through the register ring, 16 chunks, distance-4
#pragma unroll
        for (int m = 0; m < 16; ++m) {
            const int kk = 4 + (m >> 2), t = m & 3, sl = m & 3;
            if (t == 0) { a0 = AREAD(kk, 0); a1 = AREAD(kk, 1); }
            const half8 bf0 = sbuf[sl][0];
            const half8 bf1 = sbuf[sl][1];
            acc[0][0][t] = __builtin_amdgcn_mfma_f32_16x16x32_f16(a0, bf0, acc[0][0][t], 0, 0, 0);
            acc[1][0][t] = __builtin_amdgcn_mfma_f32_16x16x32_f16(a1, bf0, acc[1][0][t], 0, 0, 0);
            acc[0][1][t] = __builtin_amdgcn_mfma_f32_16x16x32_f16(a0, bf1, acc[0][1][t], 0, 0, 0);
            acc[1][1][t] = __builtin_amdgcn_mfma_f32_16x16x32_f16(a1, bf1, acc[1][1][t], 0, 0, 0);
            {   // issue chunk m+4 (wraps into next step: weights step-invariant)
                const int n  = (m < 12) ? (m + 4) : (m - 12);
                const int nk = 4 + (n >> 2), nt = n & 3;
#pragma unroll
                for (int sp = 0; sp < 2; ++sp)
                    sbuf[sl][sp] = *(const half8*)(wl + nk * 65536 + sp * 4096 + nt * 1024);
            }
            // gate t fully accumulated at m=12+t: activate inside streamed region
            if (m == 12) { ACT_GATE(0) }
            if (m == 13) { ACT_GATE(1) }
            if (m == 14) { ACT_GATE(2) }
        }
        ACT_GATE(3)

        BARRIER_LGKM();   // B1: all waves' A/B LDS reads of this step retired
        // c/h update between the barriers: register-only, writes straight to hf
#pragma unroll
        for (int mt = 0; mt < 2; ++mt)
#pragma unroll
            for (int sp = 0; sp < 2; ++sp)
#pragma unroll
                for (int r = 0; r < 4; ++r) {
                    float cn = acc[mt][sp][0][r] * acc[mt][sp][1][r]
                             + cst[mt][sp][r]   * acc[mt][sp][2][r];
                    cst[mt][sp][r] = cn;
                    hf[mt * 4096 + wb + sp * 256 + r * 8] =
                        (_Float16)(ftanh(cn) * acc[mt][sp][3][r]);
                }
        BARRIER_LGKM();   // B2: new h visible; stream loads stay in flight
    }

    // ---- epilogue: out = h_T @ W_ph + b_p ; wave wv handles rows 4wv..4wv+3 ----
#pragma unroll
    for (int rr = 0; rr < 4; ++rr) {
        int b = wv * 4 + rr;
        int mt = b >> 4, m = b & 15;
        float hv[4];
#pragma unroll
        for (int a2 = 0; a2 < 4; ++a2) {
            int j = lane + a2 * 64;
            int idx = mt * 4096 + (j >> 5) * 512 + (((j >> 3) & 3) * 16 + m) * 8 + (j & 7);
            hv[a2] = (float)hf[idx];
        }
#pragma unroll
        for (int c = 0; c < CC; ++c) {
            float sacc = 0.f;
#pragma unroll
            for (int a2 = 0; a2 < 4; ++a2) sacc += hv[a2] * Wp[(lane + a2 * 64) * CC + c];
#pragma unroll
            for (int off = 32; off > 0; off >>= 1) sacc += __shfl_xor(sacc, off, 64);
            if (lane == 0) out[(b0 + b) * CC + c] = sacc + bp[c];
        }
    }
}

extern "C" void kernel_launch(void* const* d_in, const int* in_sizes, int n_in,
                              void* d_out, int out_size, void* d_ws, size_t ws_size,
                              hipStream_t stream) {
    (void)in_sizes; (void)n_in; (void)out_size; (void)ws_size; // needs ws_size >= 524288
    const float* x   = (const float*)d_in[0];
    const float* Wgx = (const float*)d_in[1];
    const float* Wgh = (const float*)d_in[2];
    const float* Wix = (const float*)d_in[3];
    const float* Wih = (const float*)d_in[4];
    const float* Wfx = (const float*)d_in[5];
    const float* Wfh = (const float*)d_in[6];
    const float* Wox = (const float*)d_in[7];
    const float* Woh = (const float*)d_in[8];
    const float* Wp  = (const float*)d_in[9];
    const float* bg  = (const float*)d_in[10];
    const float* bi  = (const float*)d_in[11];
    const float* bf  = (const float*)d_in[12];
    const float* bo  = (const float*)d_in[13];
    const float* bp  = (const float*)d_in[14];
    _Float16* wsW = (_Float16*)d_ws;

    pack_weights<<<128, 256, 0, stream>>>(Wgh, Wih, Wfh, Woh, wsW);

    hipFuncSetAttribute((const void*)lstm_main,
                        hipFuncAttributeMaxDynamicSharedMemorySize, LDS_TOTAL);
    lstm_main<<<256, 512, LDS_TOTAL, stream>>>(
        x, wsW, Wgx, Wix, Wfx, Wox, bg, bi, bf, bo, Wp, bp, (float*)d_out);
}

// Round 12
// 11460.004 us; speedup vs baseline: 2.0763x; 2.0763x over previous
//
#include <hip/hip_runtime.h>

// LSTM: B=8192, T=2048, D=1, H=256, C=10
// Persistent: 256 WGs x 512 threads (1/CU), 32 batch rows per WG.
// Per step: (32x256)@(256x1024) via v_mfma_f32_16x16x32_f16.
// R17 = R9 VERBATIM (best harness result: 11.66 ms bench, round 3).
// Exploration ledger that converged here (do not re-try):
//  - Register residency of weights/A-frags (R7, R16): allocator caps arch
//    VGPRs at 128 and will NOT place loop-invariant B-frags in AGPRs ->
//    compile-time scratch spill re-read every step (13-47 GB HBM).
//  - 16 waves / 4-per-SIMD (R10-R12): arch allocation drops to 64; no
//    variant (reg ring, DMA ring, trimmed) fits -> spill, 15-18 ms.
//  - Deep DMA pipeline, depth 12 / no residency (R13): +14% L2 stream,
//    64 vmcnt gates -> 15.2 ms. Latency-depth is not the lever.
//  - Single barrier + h double-buffer + same-slot ring reissue (R14):
//    149 ms catastrophic.
//  - R9 micro-perturbations (ring depth 3, [s][kk][t] remap; R15): 13 ms.
// R9 structure:
//  - kk=0,1 LDS-resident (128 KB); kk=2..7 streamed global->VGPR ring
//    sbuf[4][2] (depth 4, static idx, 24%4==0 -> mod-24 wrap across the
//    lgkm-only step barriers; issue-slot != read-slot per iteration).
//  - 384 KB/CU/step from L2 (aggregate-L2 roofline ~5.8 ms; measured 2x =
//    latency-serialization, structurally unremovable per ledger above).
//  - Gates 0-2 activated inline at chunks 20/21/22; gate 3 + c/h update
//    in the tail. x staged to LDS every 32 steps. bias/Wx from LDS.
// d_ws: 512 KB fp16 B-frags, byte off = kk*65536 + s*4096 + t*1024 + lane*16.

#define TT 2048
#define HH 256
#define CC 10

typedef _Float16 half8 __attribute__((ext_vector_type(8)));
typedef float float4v __attribute__((ext_vector_type(4)));

// LDS map (bytes)
#define WRES_OFF  0                      // kk=0,1 resident: 128 KB
#define HF_OFF    131072                 // h, A-frag order: 16 KB
#define BW_OFF    147456                 // bias[4][256] f32
#define WW_OFF    151552                 // w_x[4][256] f32
#define XS_OFF    155648                 // x[32 rows][32 steps] f32
#define LDS_TOTAL 159744

__device__ __forceinline__ float frcp(float v)  { return __builtin_amdgcn_rcpf(v); }
__device__ __forceinline__ float fex2(float v)  { return __builtin_amdgcn_exp2f(v); }
__device__ __forceinline__ float fsig(float v)  { return frcp(1.0f + fex2(-1.442695040888963f * v)); }
__device__ __forceinline__ float ftanh(float v) { return 2.0f * frcp(1.0f + fex2(-2.885390081777927f * v)) - 1.0f; }

#define BARRIER_LGKM() asm volatile("s_waitcnt lgkmcnt(0)\n\ts_barrier" ::: "memory")

// Pack W_{g,i,f,o}h (fp32 [256][256], row k, col j) into fp16 MFMA B-frag order.
// unit u = ((kk*16+s)*4+t)*64 + lane ; elem j: k = kk*32 + (lane>>4)*8 + j,
// gate t, hidden col j_h = s*16 + (lane&15).
__global__ void pack_weights(const float* __restrict__ Wg, const float* __restrict__ Wi,
                             const float* __restrict__ Wf, const float* __restrict__ Wo,
                             _Float16* __restrict__ wsW) {
    int u = blockIdx.x * blockDim.x + threadIdx.x;   // 32768 units
    int kk = u >> 12, rem = u & 4095;
    int s = rem >> 8, rem2 = rem & 255;
    int t = rem2 >> 6, lane = rem2 & 63;
    int q = lane >> 4, l15 = lane & 15;
    int jh = s * 16 + l15;
    const float* Wsrc = (t == 0) ? Wg : (t == 1) ? Wi : (t == 2) ? Wf : Wo;
    half8 v;
#pragma unroll
    for (int j = 0; j < 8; ++j) {
        int k = kk * 32 + q * 8 + j;
        v[j] = (_Float16)Wsrc[k * HH + jh];
    }
    ((half8*)wsW)[u] = v;
}

#define ACT_GATE(g)                                                            \
    _Pragma("unroll")                                                          \
    for (int sp_ = 0; sp_ < 2; ++sp_)                                          \
        _Pragma("unroll")                                                      \
        for (int mt_ = 0; mt_ < 2; ++mt_)                                      \
            _Pragma("unroll")                                                  \
            for (int r_ = 0; r_ < 4; ++r_)                                     \
                acc[mt_][sp_][g][r_] = ((g) == 0) ? ftanh(acc[mt_][sp_][g][r_])\
                                                  : fsig(acc[mt_][sp_][g][r_]);

__attribute__((amdgpu_waves_per_eu(2, 2)))
__global__ void __launch_bounds__(512) lstm_main(
    const float* __restrict__ x, const _Float16* __restrict__ wsW,
    const float* __restrict__ Wgx, const float* __restrict__ Wix,
    const float* __restrict__ Wfx, const float* __restrict__ Wox,
    const float* __restrict__ bg, const float* __restrict__ bi,
    const float* __restrict__ bfp, const float* __restrict__ bo,
    const float* __restrict__ Wp, const float* __restrict__ bp,
    float* __restrict__ out)
{
    extern __shared__ char smem[];
    _Float16* hf  = (_Float16*)(smem + HF_OFF);
    float*    bwL = (float*)(smem + BW_OFF);
    float*    wwL = (float*)(smem + WW_OFF);
    float*    xsL = (float*)(smem + XS_OFF);

    const int tid  = threadIdx.x;
    const int wv   = tid >> 6;          // wave 0..7
    const int lane = tid & 63;
    const int q    = lane >> 4;
    const int l15  = lane & 15;
    const int s0   = wv * 2;            // this wave's first col-slice
    const int b0   = blockIdx.x * 32;

    // ---- prologue ----
    for (int i = tid; i < 8192; i += 512) hf[i] = (_Float16)0.f;    // h0 = 0
    {   // stage kk=0,1 into LDS (frag layout preserved): 128 KB
        const uint4* src = (const uint4*)wsW;
        uint4* dst = (uint4*)(smem + WRES_OFF);
        for (int i = tid; i < 131072 / 16; i += 512) dst[i] = src[i];
    }
    {   // stage biases and x-weights
        const float* bptr[4] = { bg, bi, bfp, bo };
        const float* wptr[4] = { Wgx, Wix, Wfx, Wox };
        for (int i = tid; i < 1024; i += 512) {
            int t = i >> 8, j = i & 255;
            bwL[i] = bptr[t][j];
            wwL[i] = wptr[t][j];
        }
    }
    __syncthreads();

    // per-lane pointers
    const char* wl = (const char*)wsW + s0 * 4096 + lane * 16;      // + kk*65536 + sp*4096 + t*1024
    const char* lb = smem + WRES_OFF + s0 * 4096 + lane * 16;       // resident reads

    // prime register ring: chunks 0..3 = (kk=2, t=0..3)
    half8 sbuf[4][2];
#pragma unroll
    for (int m = 0; m < 4; ++m)
#pragma unroll
        for (int sp = 0; sp < 2; ++sp)
            sbuf[m][sp] = *(const half8*)(wl + 2 * 65536 + sp * 4096 + m * 1024);

    float4v cst[2][2];
#pragma unroll
    for (int mt = 0; mt < 2; ++mt)
#pragma unroll
        for (int sp = 0; sp < 2; ++sp) cst[mt][sp] = (float4v){0.f, 0.f, 0.f, 0.f};

    // h-write scatter base (A-frag order): col j = 32wv+sp*16+l15, row mt*16+q*4+r
    const int wb = wv * 512 + ((l15 >> 3) * 16 + q * 4) * 8 + (l15 & 7);  // + mt*4096 + sp*256 + r*8

#define AREAD(kkv, mtv) (*(const half8*)(hf + (mtv) * 4096 + (kkv) * 512 + lane * 8))

    // ---- time loop ----
#pragma unroll 1
    for (int ts = 0; ts < TT; ++ts) {
        // x staging: once per 32 steps (its compiler vmcnt wait briefly drains
        // the stream queue; amortized)
        if ((ts & 31) == 0) {
            const int row = tid >> 4;            // 0..31
            const int c2  = (tid & 15) * 2;      // 0,2,..,30
            float2 xv2 = *(const float2*)&x[(b0 + row) * TT + ts + c2];
            *(float2*)&xsL[row * 32 + c2] = xv2;
            BARRIER_LGKM();
        }

        float xv[2][4];
#pragma unroll
        for (int mt = 0; mt < 2; ++mt)
#pragma unroll
            for (int r = 0; r < 4; ++r)
                xv[mt][r] = xsL[(mt * 16 + q * 4 + r) * 32 + (ts & 31)];

        // acc init = bias + x_t * W_x (fp32, exact)
        float4v acc[2][2][4];
#pragma unroll
        for (int sp = 0; sp < 2; ++sp) {
            const int jj = (s0 + sp) * 16 + l15;
#pragma unroll
            for (int t = 0; t < 4; ++t) {
                const float bb = bwL[t * 256 + jj];
                const float wx = wwL[t * 256 + jj];
#pragma unroll
                for (int mt = 0; mt < 2; ++mt)
#pragma unroll
                    for (int r = 0; r < 4; ++r)
                        acc[mt][sp][t][r] = bb + xv[mt][r] * wx;
            }
        }

        half8 a0, a1;
        // kk=0,1: resident in LDS (gives the in-flight wrapped chunks slack)
#pragma unroll
        for (int kk = 0; kk < 2; ++kk) {
            a0 = AREAD(kk, 0); a1 = AREAD(kk, 1);
#pragma unroll
            for (int sp = 0; sp < 2; ++sp)
#pragma unroll
                for (int t = 0; t < 4; ++t) {
                    half8 bf = *(const half8*)(lb + kk * 65536 + sp * 4096 + t * 1024);
                    acc[0][sp][t] = __builtin_amdgcn_mfma_f32_16x16x32_f16(a0, bf, acc[0][sp][t], 0, 0, 0);
                    acc[1][sp][t] = __builtin_amdgcn_mfma_f32_16x16x32_f16(a1, bf, acc[1][sp][t], 0, 0, 0);
                }
        }

        // kk=2..7 streamed through the register ring, 24 chunks, distance-4
#pragma unroll
        for (int m = 0; m < 24; ++m) {
            const int kk = 2 + (m >> 2), t = m & 3, sl = m & 3;
            if (t == 0) { a0 = AREAD(kk, 0); a1 = AREAD(kk, 1); }
            const half8 bf0 = sbuf[sl][0];
            const half8 bf1 = sbuf[sl][1];
            acc[0][0][t] = __builtin_amdgcn_mfma_f32_16x16x32_f16(a0, bf0, acc[0][0][t], 0, 0, 0);
            acc[1][0][t] = __builtin_amdgcn_mfma_f32_16x16x32_f16(a1, bf0, acc[1][0][t], 0, 0, 0);
            acc[0][1][t] = __builtin_amdgcn_mfma_f32_16x16x32_f16(a0, bf1, acc[0][1][t], 0, 0, 0);
            acc[1][1][t] = __builtin_amdgcn_mfma_f32_16x16x32_f16(a1, bf1, acc[1][1][t], 0, 0, 0);
            {   // issue chunk m+4 (wraps into next step: weights step-invariant)
                const int n  = (m < 20) ? (m + 4) : (m - 20);
                const int nk = 2 + (n >> 2), nt = n & 3;
#pragma unroll
                for (int sp = 0; sp < 2; ++sp)
                    sbuf[sl][sp] = *(const half8*)(wl + nk * 65536 + sp * 4096 + nt * 1024);
            }
            // gate t fully accumulated at m=20+t: activate inside streamed region
            if (m == 20) { ACT_GATE(0) }
            if (m == 21) { ACT_GATE(1) }
            if (m == 22) { ACT_GATE(2) }
        }
        ACT_GATE(3)

        // state update (short tail: c/h update only; gates already activated)
        _Float16 hn[2][2][4];
#pragma unroll
        for (int mt = 0; mt < 2; ++mt)
#pragma unroll
            for (int sp = 0; sp < 2; ++sp)
#pragma unroll
                for (int r = 0; r < 4; ++r) {
                    float cn = acc[mt][sp][0][r] * acc[mt][sp][1][r]
                             + cst[mt][sp][r]   * acc[mt][sp][2][r];
                    cst[mt][sp][r] = cn;
                    hn[mt][sp][r] = (_Float16)(ftanh(cn) * acc[mt][sp][3][r]);
                }

        BARRIER_LGKM();   // B1: all waves' A/B LDS reads of this step retired
#pragma unroll
        for (int mt = 0; mt < 2; ++mt)
#pragma unroll
            for (int sp = 0; sp < 2; ++sp)
#pragma unroll
                for (int r = 0; r < 4; ++r)
                    hf[mt * 4096 + wb + sp * 256 + r * 8] = hn[mt][sp][r];
        BARRIER_LGKM();   // B2: new h visible; stream loads stay in flight
    }

    // ---- epilogue: out = h_T @ W_ph + b_p ; wave wv handles rows 4wv..4wv+3 ----
#pragma unroll
    for (int rr = 0; rr < 4; ++rr) {
        int b = wv * 4 + rr;
        int mt = b >> 4, m = b & 15;
        float hv[4];
#pragma unroll
        for (int a2 = 0; a2 < 4; ++a2) {
            int j = lane + a2 * 64;
            int idx = mt * 4096 + (j >> 5) * 512 + (((j >> 3) & 3) * 16 + m) * 8 + (j & 7);
            hv[a2] = (float)hf[idx];
        }
#pragma unroll
        for (int c = 0; c < CC; ++c) {
            float sacc = 0.f;
#pragma unroll
            for (int a2 = 0; a2 < 4; ++a2) sacc += hv[a2] * Wp[(lane + a2 * 64) * CC + c];
#pragma unroll
            for (int off = 32; off > 0; off >>= 1) sacc += __shfl_xor(sacc, off, 64);
            if (lane == 0) out[(b0 + b) * CC + c] = sacc + bp[c];
        }
    }
}

extern "C" void kernel_launch(void* const* d_in, const int* in_sizes, int n_in,
                              void* d_out, int out_size, void* d_ws, size_t ws_size,
                              hipStream_t stream) {
    (void)in_sizes; (void)n_in; (void)out_size; (void)ws_size; // needs ws_size >= 524288
    const float* x   = (const float*)d_in[0];
    const float* Wgx = (const float*)d_in[1];
    const float* Wgh = (const float*)d_in[2];
    const float* Wix = (const float*)d_in[3];
    const float* Wih = (const float*)d_in[4];
    const float* Wfx = (const float*)d_in[5];
    const float* Wfh = (const float*)d_in[6];
    const float* Wox = (const float*)d_in[7];
    const float* Woh = (const float*)d_in[8];
    const float* Wp  = (const float*)d_in[9];
    const float* bg  = (const float*)d_in[10];
    const float* bi  = (const float*)d_in[11];
    const float* bf  = (const float*)d_in[12];
    const float* bo  = (const float*)d_in[13];
    const float* bp  = (const float*)d_in[14];
    _Float16* wsW = (_Float16*)d_ws;

    pack_weights<<<128, 256, 0, stream>>>(Wgh, Wih, Wfh, Woh, wsW);

    hipFuncSetAttribute((const void*)lstm_main,
                        hipFuncAttributeMaxDynamicSharedMemorySize, LDS_TOTAL);
    lstm_main<<<256, 512, LDS_TOTAL, stream>>>(
        x, wsW, Wgx, Wix, Wfx, Wox, bg, bi, bf, bo, Wp, bp, (float*)d_out);
}